// Round 1
// baseline (218.282 us; speedup 1.0000x reference)
//
#include <hip/hip_runtime.h>

#define D 128
#define GG 8            // nodes per matvec block
#define RS_STRIDE 256   // floats (1 KiB) between result slots -> spread L2 channels

__device__ __forceinline__ int lower_bound_dev(const int* __restrict__ a, int n, int v) {
    int lo = 0, hi = n;
    while (lo < hi) {
        int mid = (lo + hi) >> 1;
        if (a[mid] < v) lo = mid + 1; else hi = mid;
    }
    return lo;
}

// Pack W,M into [k/4][d][4] so matvec lanes load W[d][k..k+3] as one float4,
// coalesced across d. Also zero the strided result accumulator slots.
__global__ void prep_kernel(const float* __restrict__ W, const float* __restrict__ M,
                            float* __restrict__ WTP, float* __restrict__ MTP,
                            float* __restrict__ rs) {
    int i = blockIdx.x * blockDim.x + threadIdx.x;   // [0, 16384)
    if (i < D * D) {
        int k4  = i >> 9;        // i / (D*4)
        int rem = i & 511;
        int d   = rem >> 2;
        int kk  = rem & 3;
        int src = d * D + (k4 << 2) + kk;
        WTP[i] = W[src];
        MTP[i] = M[src];
    }
    if (i < D) rs[i * RS_STRIDE] = 0.0f;
}

// One 64-thread block per node: binary search sorted segment_ids for this
// node's edge range, gather-sum emb rows (float4/lane, 2 edge-groups, 2x unroll).
__global__ void agg_kernel(const int* __restrict__ nbr, const int* __restrict__ seg,
                           const float* __restrict__ emb, float* __restrict__ agg,
                           int E) {
    int n = blockIdx.x;
    int t = threadIdx.x;        // 0..63
    int c = t & 31;             // float4 chunk within the row
    int j = t >> 5;             // edge group 0/1

    int lo = lower_bound_dev(seg, E, n);
    int hi = lower_bound_dev(seg, E, n + 1);

    float4 a0 = make_float4(0.f, 0.f, 0.f, 0.f);
    float4 a1 = make_float4(0.f, 0.f, 0.f, 0.f);

    int e = lo + j;             // group j covers lo+j, lo+j+2, ...
    for (; e + 2 < hi; e += 4) {
        int nid0 = nbr[e];
        int nid1 = nbr[e + 2];
        float4 v0 = *(const float4*)&emb[(size_t)nid0 * D + (c << 2)];
        float4 v1 = *(const float4*)&emb[(size_t)nid1 * D + (c << 2)];
        a0.x += v0.x; a0.y += v0.y; a0.z += v0.z; a0.w += v0.w;
        a1.x += v1.x; a1.y += v1.y; a1.z += v1.z; a1.w += v1.w;
    }
    if (e < hi) {
        float4 v = *(const float4*)&emb[(size_t)nbr[e] * D + (c << 2)];
        a0.x += v.x; a0.y += v.y; a0.z += v.z; a0.w += v.w;
    }
    a0.x += a1.x; a0.y += a1.y; a0.z += a1.z; a0.w += a1.w;

    // fold group 1 into group 0 (lanes t and t^32 hold same chunk c)
    a0.x += __shfl_xor(a0.x, 32);
    a0.y += __shfl_xor(a0.y, 32);
    a0.z += __shfl_xor(a0.z, 32);
    a0.w += __shfl_xor(a0.w, 32);

    if (j == 0) *(float4*)&agg[(size_t)n * D + (c << 2)] = a0;
}

// Block = 1 wave, 8 nodes. Stage x (self emb) and a (agg) in LDS, each lane
// owns output dims t and t+64, fp32 FMA matvec with packed W/M, relu,
// block-partial sum, strided atomicAdd into result vector.
__global__ void matvec_kernel(const int* __restrict__ node_ids,
                              const float* __restrict__ emb,
                              const float* __restrict__ agg,
                              const float* __restrict__ WTP,
                              const float* __restrict__ MTP,
                              float* __restrict__ rs, int N) {
    __shared__ __align__(16) float xs[GG][D];
    __shared__ __align__(16) float as[GG][D];

    int t = threadIdx.x;                 // 0..63
    int base = blockIdx.x * GG;
    int cnt = min(GG, N - base);

    for (int g = 0; g < cnt; ++g) {
        int nid = node_ids[base + g];
        ((float2*)xs[g])[t] = ((const float2*)(emb + (size_t)nid * D))[t];
        ((float2*)as[g])[t] = ((const float2*)(agg + (size_t)(base + g) * D))[t];
    }
    __syncthreads();

    float acc0[GG], acc1[GG];
#pragma unroll
    for (int g = 0; g < GG; ++g) { acc0[g] = 0.f; acc1[g] = 0.f; }

#pragma unroll 2
    for (int k4 = 0; k4 < D / 4; ++k4) {
        float4 w0 = *(const float4*)&WTP[(k4 << 9) + (t << 2)];
        float4 w1 = *(const float4*)&WTP[(k4 << 9) + ((t + 64) << 2)];
        float4 m0 = *(const float4*)&MTP[(k4 << 9) + (t << 2)];
        float4 m1 = *(const float4*)&MTP[(k4 << 9) + ((t + 64) << 2)];
#pragma unroll
        for (int g = 0; g < GG; ++g) {
            float4 xv = *(const float4*)&xs[g][k4 << 2];
            float4 av = *(const float4*)&as[g][k4 << 2];
            acc0[g] += w0.x * xv.x + w0.y * xv.y + w0.z * xv.z + w0.w * xv.w
                     + m0.x * av.x + m0.y * av.y + m0.z * av.z + m0.w * av.w;
            acc1[g] += w1.x * xv.x + w1.y * xv.y + w1.z * xv.z + w1.w * xv.w
                     + m1.x * av.x + m1.y * av.y + m1.z * av.z + m1.w * av.w;
        }
    }

    float p0 = 0.f, p1 = 0.f;
    for (int g = 0; g < cnt; ++g) {
        p0 += fmaxf(acc0[g], 0.f);
        p1 += fmaxf(acc1[g], 0.f);
    }
    atomicAdd(&rs[t * RS_STRIDE], p0);
    atomicAdd(&rs[(t + 64) * RS_STRIDE], p1);
}

__global__ void softmax_kernel(const float* __restrict__ rs, float* __restrict__ out) {
    int t = threadIdx.x;                 // 0..63
    float v0 = rs[t * RS_STRIDE];
    float v1 = rs[(t + 64) * RS_STRIDE];
    float m = fmaxf(v0, v1);
    for (int o = 32; o > 0; o >>= 1) m = fmaxf(m, __shfl_xor(m, o));
    float e0 = expf(v0 - m);
    float e1 = expf(v1 - m);
    float s = e0 + e1;
    for (int o = 32; o > 0; o >>= 1) s += __shfl_xor(s, o);
    float inv = 1.0f / s;
    out[t] = e0 * inv;
    out[t + 64] = e1 * inv;
}

extern "C" void kernel_launch(void* const* d_in, const int* in_sizes, int n_in,
                              void* d_out, int out_size, void* d_ws, size_t ws_size,
                              hipStream_t stream) {
    const int*   node_ids = (const int*)d_in[0];
    const int*   nbr      = (const int*)d_in[1];
    const int*   seg      = (const int*)d_in[2];
    const float* W        = (const float*)d_in[3];
    const float* M        = (const float*)d_in[4];
    const float* emb      = (const float*)d_in[5];
    float* out = (float*)d_out;

    int N = in_sizes[0];
    int E = in_sizes[1];

    // workspace layout (floats): agg[N*D] | WTP[D*D] | MTP[D*D] | rs[D*RS_STRIDE]
    float* ws  = (float*)d_ws;
    float* agg = ws;
    float* WTP = agg + (size_t)N * D;
    float* MTP = WTP + D * D;
    float* rs  = MTP + D * D;

    prep_kernel<<<(D * D + 255) / 256, 256, 0, stream>>>(W, M, WTP, MTP, rs);
    agg_kernel<<<N, 64, 0, stream>>>(nbr, seg, emb, agg, E);
    matvec_kernel<<<(N + GG - 1) / GG, 64, 0, stream>>>(node_ids, emb, agg, WTP, MTP, rs, N);
    softmax_kernel<<<1, 64, 0, stream>>>(rs, out);
}

// Round 2
// 206.939 us; speedup vs baseline: 1.0548x; 1.0548x over previous
//
#include <hip/hip_runtime.h>

#define D 128
#define GG 8            // nodes per wave-group in matvec
#define MV_WAVES 4      // waves per matvec block
#define MV_BLOCKS 256   // one block per CU (LDS-capped anyway)
#define RS_STRIDE 256   // floats (1 KiB) between result slots -> spread L2 channels

// -------------------------------------------------------------------------
// Build row_ptr[N+1] from sorted segment_ids (removes per-node binary search)
// and zero the strided result accumulator.
__global__ void rowptr_kernel(const int* __restrict__ seg, int* __restrict__ row_ptr,
                              float* __restrict__ rs, int E, int N) {
    int e = blockIdx.x * blockDim.x + threadIdx.x;
    if (e < D) rs[e * RS_STRIDE] = 0.0f;
    if (e >= E) return;
    int s = seg[e];
    if (e == 0) {
        for (int n = 0; n <= s; ++n) row_ptr[n] = 0;
    } else {
        int sp = seg[e - 1];
        for (int n = sp + 1; n <= s; ++n) row_ptr[n] = e;
    }
    if (e == E - 1) {
        for (int n = s + 1; n <= N; ++n) row_ptr[n] = E;
    }
}

// -------------------------------------------------------------------------
// Segment-sum of raw embeddings. 256-thread block = 4 nodes; per node:
// 16 lanes per edge (32 B/lane), 4 edges in flight for MLP.
__global__ void agg_kernel(const int* __restrict__ nbr, const int* __restrict__ row_ptr,
                           const float* __restrict__ emb, float* __restrict__ agg, int N) {
    int n = blockIdx.x * 4 + (threadIdx.x >> 6);
    if (n >= N) return;
    int tt = threadIdx.x & 63;
    int c = tt & 15;          // chunk: float4 pair (c, c+16)
    int j = tt >> 4;          // edge group 0..3

    int lo = row_ptr[n];
    int hi = row_ptr[n + 1];

    float4 s0 = make_float4(0.f, 0.f, 0.f, 0.f);
    float4 s1 = make_float4(0.f, 0.f, 0.f, 0.f);
    for (int e = lo + j; e < hi; e += 4) {
        const float4* r = (const float4*)&emb[(size_t)nbr[e] * D];
        float4 v0 = r[c];
        float4 v1 = r[c + 16];
        s0.x += v0.x; s0.y += v0.y; s0.z += v0.z; s0.w += v0.w;
        s1.x += v1.x; s1.y += v1.y; s1.z += v1.z; s1.w += v1.w;
    }
    // fold the 4 edge groups (lanes with same c differ in bits 4,5 of tt)
    s0.x += __shfl_xor(s0.x, 16); s0.y += __shfl_xor(s0.y, 16);
    s0.z += __shfl_xor(s0.z, 16); s0.w += __shfl_xor(s0.w, 16);
    s1.x += __shfl_xor(s1.x, 16); s1.y += __shfl_xor(s1.y, 16);
    s1.z += __shfl_xor(s1.z, 16); s1.w += __shfl_xor(s1.w, 16);
    s0.x += __shfl_xor(s0.x, 32); s0.y += __shfl_xor(s0.y, 32);
    s0.z += __shfl_xor(s0.z, 32); s0.w += __shfl_xor(s0.w, 32);
    s1.x += __shfl_xor(s1.x, 32); s1.y += __shfl_xor(s1.y, 32);
    s1.z += __shfl_xor(s1.z, 32); s1.w += __shfl_xor(s1.w, 32);

    if (j == 0) {
        float4* o = (float4*)&agg[(size_t)n * D];
        o[c] = s0;
        o[c + 16] = s1;
    }
}

// -------------------------------------------------------------------------
// LDS layout (floats):
//   [    0,16384)  Wp packed [k4][d][4]   (64 KB)
//   [16384,32768)  Mp packed [k4][d][4]   (64 KB)
//   [32768,40960)  x|a staging, 2048 floats per wave: 8 nodes x (x[128]|a[128])
// Total 163840 B = full 160 KiB GROUP segment -> 1 block/CU, 4 waves.
// Each wave grid-strides over 8-node groups; weights staged once per block.
__global__ __launch_bounds__(256, 1) void matvec_kernel(
    const int* __restrict__ node_ids, const float* __restrict__ emb,
    const float* __restrict__ agg, const float* __restrict__ W,
    const float* __restrict__ M, float* __restrict__ rs, int N, int ngroups) {
    extern __shared__ float lds[];
    float4* L4 = (float4*)lds;
    int t = threadIdx.x;

    // Stage W,M global->LDS with on-the-fly pack: Wp[k4][d][0..3] = W[d][4k4..4k4+3].
    // Lane layout chosen for conflict-free LDS writes (contiguous in d).
    const float4* W4 = (const float4*)W;
    const float4* M4 = (const float4*)M;
    for (int idx = t; idx < 4096; idx += 256) {
        int k4 = idx >> 7;          // 0..31
        int d  = idx & 127;
        L4[(k4 << 7) + d]        = W4[d * 32 + k4];
        L4[4096 + (k4 << 7) + d] = M4[d * 32 + k4];
    }
    __syncthreads();

    int wave = t >> 6;
    int l = t & 63;
    float4* xa4 = (float4*)(lds + 32768 + (wave << 11));  // wave-private, no barriers

    float pr0 = 0.f, pr1 = 0.f;

    for (int grp = blockIdx.x * MV_WAVES + wave; grp < ngroups; grp += MV_BLOCKS * MV_WAVES) {
        int base = grp * GG;
        // stage x|a for 8 nodes: lanes 0..31 -> x chunk l, lanes 32..63 -> a chunk l-32
        for (int g = 0; g < GG; ++g) {
            int node = base + g;
            if (node > N - 1) node = N - 1;
            float4 v;
            if (l < 32) v = ((const float4*)&emb[(size_t)node_ids[node] * D])[l];
            else        v = ((const float4*)&agg[(size_t)node * D])[l - 32];
            xa4[(g << 6) + l] = v;
        }

        float acc0[GG], acc1[GG];
#pragma unroll
        for (int g = 0; g < GG; ++g) { acc0[g] = 0.f; acc1[g] = 0.f; }

#pragma unroll 4
        for (int k4 = 0; k4 < 32; ++k4) {
            float4 w0 = L4[(k4 << 7) + l];
            float4 w1 = L4[(k4 << 7) + l + 64];
            float4 m0 = L4[4096 + (k4 << 7) + l];
            float4 m1 = L4[4096 + (k4 << 7) + l + 64];
#pragma unroll
            for (int g = 0; g < GG; ++g) {
                float4 xv = xa4[(g << 6) + k4];
                float4 av = xa4[(g << 6) + 32 + k4];
                acc0[g] += w0.x * xv.x + w0.y * xv.y + w0.z * xv.z + w0.w * xv.w
                         + m0.x * av.x + m0.y * av.y + m0.z * av.z + m0.w * av.w;
                acc1[g] += w1.x * xv.x + w1.y * xv.y + w1.z * xv.z + w1.w * xv.w
                         + m1.x * av.x + m1.y * av.y + m1.z * av.z + m1.w * av.w;
            }
        }

        int cnt = N - base; if (cnt > GG) cnt = GG;
        for (int g = 0; g < cnt; ++g) {
            pr0 += fmaxf(acc0[g], 0.f);
            pr1 += fmaxf(acc1[g], 0.f);
        }
    }
    atomicAdd(&rs[l * RS_STRIDE], pr0);
    atomicAdd(&rs[(l + 64) * RS_STRIDE], pr1);
}

// -------------------------------------------------------------------------
__global__ void softmax_kernel(const float* __restrict__ rs, float* __restrict__ out) {
    int t = threadIdx.x;                 // 0..63
    float v0 = rs[t * RS_STRIDE];
    float v1 = rs[(t + 64) * RS_STRIDE];
    float m = fmaxf(v0, v1);
    for (int o = 32; o > 0; o >>= 1) m = fmaxf(m, __shfl_xor(m, o));
    float e0 = expf(v0 - m);
    float e1 = expf(v1 - m);
    float s = e0 + e1;
    for (int o = 32; o > 0; o >>= 1) s += __shfl_xor(s, o);
    float inv = 1.0f / s;
    out[t] = e0 * inv;
    out[t + 64] = e1 * inv;
}

extern "C" void kernel_launch(void* const* d_in, const int* in_sizes, int n_in,
                              void* d_out, int out_size, void* d_ws, size_t ws_size,
                              hipStream_t stream) {
    const int*   node_ids = (const int*)d_in[0];
    const int*   nbr      = (const int*)d_in[1];
    const int*   seg      = (const int*)d_in[2];
    const float* W        = (const float*)d_in[3];
    const float* M        = (const float*)d_in[4];
    const float* emb      = (const float*)d_in[5];
    float* out = (float*)d_out;

    int N = in_sizes[0];
    int E = in_sizes[1];
    int ngroups = (N + GG - 1) / GG;

    // ws layout (floats): agg[N*D] | rs[D*RS_STRIDE] | row_ptr[N+1] (ints)
    float* ws  = (float*)d_ws;
    float* agg = ws;
    float* rs  = agg + (size_t)N * D;
    int*   row_ptr = (int*)(rs + (size_t)D * RS_STRIDE);

    // opt-in to >64KB dynamic LDS (no-op if not needed; not a stream op)
    static int attr_done = 0;
    if (!attr_done) {
        (void)hipFuncSetAttribute((const void*)matvec_kernel,
                                  hipFuncAttributeMaxDynamicSharedMemorySize, 163840);
        attr_done = 1;
    }

    rowptr_kernel<<<(E + 255) / 256, 256, 0, stream>>>(seg, row_ptr, rs, E, N);
    agg_kernel<<<(N + 3) / 4, 256, 0, stream>>>(nbr, row_ptr, emb, agg, N);
    matvec_kernel<<<MV_BLOCKS, 256, 163840, stream>>>(node_ids, emb, agg, W, M, rs, N, ngroups);
    softmax_kernel<<<1, 64, 0, stream>>>(rs, out);
}

// Round 3
// 155.766 us; speedup vs baseline: 1.4013x; 1.3285x over previous
//
#include <hip/hip_runtime.h>

#define D 128
#define RS_STRIDE 64      // floats (256 B) between result slots
#define MV_BLOCKS 1024    // 4096 waves: dt = wid&7, stripe = wid>>3 (512 stripes)

typedef __attribute__((ext_vector_type(8))) short bf16x8;
typedef __attribute__((ext_vector_type(4))) float f32x4;

__device__ __forceinline__ unsigned short f2bf(float f) {
    unsigned u = __float_as_uint(f);
    unsigned r = (u + 0x7fffu + ((u >> 16) & 1u)) >> 16;
    return (unsigned short)r;
}
__device__ __forceinline__ ushort4 pack4(float4 v) {
    ushort4 o; o.x = f2bf(v.x); o.y = f2bf(v.y); o.z = f2bf(v.z); o.w = f2bf(v.w);
    return o;
}
__device__ __forceinline__ void red3(float& x) {
    x += __shfl_xor(x, 8);
    x += __shfl_xor(x, 16);
    x += __shfl_xor(x, 32);
}

// -------------------------------------------------------------------------
// row_ptr[N+1] from sorted segment_ids; zero strided result accumulator.
__global__ void rowptr_kernel(const int* __restrict__ seg, int* __restrict__ row_ptr,
                              float* __restrict__ rs, int E, int N) {
    int e = blockIdx.x * blockDim.x + threadIdx.x;
    if (e < D) rs[e * RS_STRIDE] = 0.0f;
    if (e >= E) return;
    int s = seg[e];
    if (e == 0) {
        for (int n = 0; n <= s; ++n) row_ptr[n] = 0;
    } else {
        int sp = seg[e - 1];
        for (int n = sp + 1; n <= s; ++n) row_ptr[n] = e;
    }
    if (e == E - 1) {
        for (int n = s + 1; n <= N; ++n) row_ptr[n] = E;
    }
}

// -------------------------------------------------------------------------
// Convert W,M fp32[128][128] row-major -> bf16 row-major.
__global__ void prep_kernel(const float* __restrict__ W, const float* __restrict__ M,
                            unsigned short* __restrict__ Wb, unsigned short* __restrict__ Mb) {
    int i = blockIdx.x * blockDim.x + threadIdx.x;
    if (i < D * D) { Wb[i] = f2bf(W[i]); Mb[i] = f2bf(M[i]); }
}

// -------------------------------------------------------------------------
// Segment-sum of raw fp32 embeddings -> bf16 aggb[N][128]; also gather
// xb[n] = bf16(emb[node_ids[n]]). Block = 4 nodes; per node: 8 edge streams
// x 8 lanes/edge, each lane owns 4 float4 chunks (c, c+8, c+16, c+24).
__global__ void agg_kernel(const int* __restrict__ node_ids, const int* __restrict__ nbr,
                           const int* __restrict__ row_ptr, const float* __restrict__ emb,
                           unsigned short* __restrict__ aggb, unsigned short* __restrict__ xb,
                           int N) {
    int n = blockIdx.x * 4 + (threadIdx.x >> 6);
    if (n >= N) return;
    int tt = threadIdx.x & 63;
    int c = tt & 7;       // chunk group
    int j = tt >> 3;      // edge stream 0..7

    int lo = row_ptr[n];
    int hi = row_ptr[n + 1];

    float4 s0 = make_float4(0.f, 0.f, 0.f, 0.f);
    float4 s1 = make_float4(0.f, 0.f, 0.f, 0.f);
    float4 s2 = make_float4(0.f, 0.f, 0.f, 0.f);
    float4 s3 = make_float4(0.f, 0.f, 0.f, 0.f);

    for (int e = lo + j; e < hi; e += 8) {
        const float4* r = (const float4*)&emb[(size_t)nbr[e] * D];
        float4 v0 = r[c], v1 = r[c + 8], v2 = r[c + 16], v3 = r[c + 24];
        s0.x += v0.x; s0.y += v0.y; s0.z += v0.z; s0.w += v0.w;
        s1.x += v1.x; s1.y += v1.y; s1.z += v1.z; s1.w += v1.w;
        s2.x += v2.x; s2.y += v2.y; s2.z += v2.z; s2.w += v2.w;
        s3.x += v3.x; s3.y += v3.y; s3.z += v3.z; s3.w += v3.w;
    }
    // fold 8 edge streams (xor over lane bits 3,4,5)
    red3(s0.x); red3(s0.y); red3(s0.z); red3(s0.w);
    red3(s1.x); red3(s1.y); red3(s1.z); red3(s1.w);
    red3(s2.x); red3(s2.y); red3(s2.z); red3(s2.w);
    red3(s3.x); red3(s3.y); red3(s3.z); red3(s3.w);

    if (j == 0) {
        ushort4* o = (ushort4*)(aggb + (size_t)n * D);
        o[c]      = pack4(s0);
        o[c + 8]  = pack4(s1);
        o[c + 16] = pack4(s2);
        o[c + 24] = pack4(s3);
    }
    if (tt < 32) {
        int nid = node_ids[n];
        float4 v = ((const float4*)&emb[(size_t)nid * D])[tt];
        ((ushort4*)(xb + (size_t)n * D))[tt] = pack4(v);
    }
}

// -------------------------------------------------------------------------
// MFMA matvec + relu + column-sum. Wave job = (dim-tile dt, node stripe).
// pre[node][dim] = sum_k X[node][k] W[dim][k] + A[node][k] M[dim][k]
// A-frag: A[m=lane&15][k=quad*8+j]; B-frag: B[k=quad*8+j][n=lane&15] = W[n][k]
// C/D: col=lane&15 (dim), row=quad*4+reg (node).
__global__ __launch_bounds__(256) void matvec_kernel(
    const unsigned short* __restrict__ xb, const unsigned short* __restrict__ aggb,
    const unsigned short* __restrict__ Wb, const unsigned short* __restrict__ Mb,
    float* __restrict__ rs, int N, int ngroups) {
    int t = threadIdx.x;
    int wid = blockIdx.x * 4 + (t >> 6);   // 0..4095
    int l = t & 63;
    int quad = l >> 4, col = l & 15;
    int dt = wid & 7;
    int stripe = wid >> 3;                 // 0..511

    bf16x8 bw[4], bm[4];
    int wrow = (dt * 16 + col) * D;
#pragma unroll
    for (int ks = 0; ks < 4; ++ks) {
        int off = wrow + ks * 32 + quad * 8;
        bw[ks] = *(const bf16x8*)(Wb + off);
        bm[ks] = *(const bf16x8*)(Mb + off);
    }

    const bf16x8 zero8 = {0, 0, 0, 0, 0, 0, 0, 0};
    float vsum = 0.f;

    for (int grp = stripe; grp < ngroups; grp += 512) {
        int node = grp * 16 + col;
        bool valid = node < N;
        const unsigned short* xr = xb + (size_t)node * D + quad * 8;
        const unsigned short* ar = aggb + (size_t)node * D + quad * 8;

        f32x4 acc = {0.f, 0.f, 0.f, 0.f};
#pragma unroll
        for (int ks = 0; ks < 4; ++ks) {
            bf16x8 ax = valid ? *(const bf16x8*)(xr + ks * 32) : zero8;
            bf16x8 aa = valid ? *(const bf16x8*)(ar + ks * 32) : zero8;
            acc = __builtin_amdgcn_mfma_f32_16x16x32_bf16(ax, bw[ks], acc, 0, 0, 0);
            acc = __builtin_amdgcn_mfma_f32_16x16x32_bf16(aa, bm[ks], acc, 0, 0, 0);
        }
        vsum += fmaxf(acc[0], 0.f) + fmaxf(acc[1], 0.f)
              + fmaxf(acc[2], 0.f) + fmaxf(acc[3], 0.f);
    }

    // fold quads: lanes sharing col
    vsum += __shfl_xor(vsum, 16);
    vsum += __shfl_xor(vsum, 32);
    if (l < 16) atomicAdd(&rs[(dt * 16 + col) * RS_STRIDE], vsum);
}

// -------------------------------------------------------------------------
__global__ void softmax_kernel(const float* __restrict__ rs, float* __restrict__ out) {
    int t = threadIdx.x;                 // 0..63
    float v0 = rs[t * RS_STRIDE];
    float v1 = rs[(t + 64) * RS_STRIDE];
    float m = fmaxf(v0, v1);
    for (int o = 32; o > 0; o >>= 1) m = fmaxf(m, __shfl_xor(m, o));
    float e0 = expf(v0 - m);
    float e1 = expf(v1 - m);
    float s = e0 + e1;
    for (int o = 32; o > 0; o >>= 1) s += __shfl_xor(s, o);
    float inv = 1.0f / s;
    out[t] = e0 * inv;
    out[t + 64] = e1 * inv;
}

extern "C" void kernel_launch(void* const* d_in, const int* in_sizes, int n_in,
                              void* d_out, int out_size, void* d_ws, size_t ws_size,
                              hipStream_t stream) {
    const int*   node_ids = (const int*)d_in[0];
    const int*   nbr      = (const int*)d_in[1];
    const int*   seg      = (const int*)d_in[2];
    const float* W        = (const float*)d_in[3];
    const float* M        = (const float*)d_in[4];
    const float* emb      = (const float*)d_in[5];
    float* out = (float*)d_out;

    int N = in_sizes[0];
    int E = in_sizes[1];
    int ngroups = (N + 15) / 16;

    // ws layout: xb[N*D] bf16 | aggb[N*D] bf16 | Wb | Mb | rs | row_ptr  (~10.4 MB)
    unsigned short* xb   = (unsigned short*)d_ws;
    unsigned short* aggb = xb + (size_t)N * D;
    unsigned short* Wb   = aggb + (size_t)N * D;
    unsigned short* Mb   = Wb + D * D;
    float* rs            = (float*)(Mb + D * D);
    int* row_ptr         = (int*)(rs + D * RS_STRIDE);

    rowptr_kernel<<<(E + 255) / 256, 256, 0, stream>>>(seg, row_ptr, rs, E, N);
    prep_kernel<<<(D * D + 255) / 256, 256, 0, stream>>>(W, M, Wb, Mb);
    agg_kernel<<<(N + 3) / 4, 256, 0, stream>>>(node_ids, nbr, row_ptr, emb, aggb, xb, N);
    matvec_kernel<<<MV_BLOCKS, 256, 0, stream>>>(xb, aggb, Wb, Mb, rs, N, ngroups);
    softmax_kernel<<<1, 64, 0, stream>>>(rs, out);
}

// Round 4
// 153.125 us; speedup vs baseline: 1.4255x; 1.0172x over previous
//
#include <hip/hip_runtime.h>

#define D 128
#define RS_STRIDE 64      // floats (256 B) between result slots

typedef __attribute__((ext_vector_type(8))) short bf16x8;
typedef __attribute__((ext_vector_type(8))) unsigned short u16x8;
typedef __attribute__((ext_vector_type(4))) float f32x4;

__device__ __forceinline__ unsigned short f2bf(float f) {
    unsigned u = __float_as_uint(f);
    unsigned r = (u + 0x7fffu + ((u >> 16) & 1u)) >> 16;
    return (unsigned short)r;
}
__device__ __forceinline__ float bf2f(unsigned short h) {
    return __uint_as_float(((unsigned)h) << 16);
}
__device__ __forceinline__ ushort4 pack4(float4 v) {
    ushort4 o; o.x = f2bf(v.x); o.y = f2bf(v.y); o.z = f2bf(v.z); o.w = f2bf(v.w);
    return o;
}
__device__ __forceinline__ void red3(float& x) {
    x += __shfl_xor(x, 8);
    x += __shfl_xor(x, 16);
    x += __shfl_xor(x, 32);
}

// -------------------------------------------------------------------------
// emb fp32 -> bf16 (if n4>0), W/M fp32 -> bf16, zero strided rs slots.
__global__ void convert_kernel(const float* __restrict__ emb, const float* __restrict__ W,
                               const float* __restrict__ M, unsigned short* __restrict__ embb,
                               unsigned short* __restrict__ Wb, unsigned short* __restrict__ Mb,
                               float* __restrict__ rs, int n4) {
    int i = blockIdx.x * blockDim.x + threadIdx.x;
    if (i < n4) ((ushort4*)embb)[i] = pack4(((const float4*)emb)[i]);
    if (i < 4096)       ((ushort4*)Wb)[i]        = pack4(((const float4*)W)[i]);
    else if (i < 8192)  ((ushort4*)Mb)[i - 4096] = pack4(((const float4*)M)[i - 4096]);
    if (i < D) rs[i * RS_STRIDE] = 0.0f;
}

// -------------------------------------------------------------------------
// row_ptr[N+1] from sorted segment_ids.
__global__ void rowptr_kernel(const int* __restrict__ seg, int* __restrict__ row_ptr,
                              int E, int N) {
    int e = blockIdx.x * blockDim.x + threadIdx.x;
    if (e >= E) return;
    int s = seg[e];
    if (e == 0) {
        for (int n = 0; n <= s; ++n) row_ptr[n] = 0;
    } else {
        int sp = seg[e - 1];
        for (int n = sp + 1; n <= s; ++n) row_ptr[n] = e;
    }
    if (e == E - 1) {
        for (int n = s + 1; n <= N; ++n) row_ptr[n] = E;
    }
}

// -------------------------------------------------------------------------
// Segment-sum of bf16 emb rows -> bf16 aggb. Block = 4 nodes; per node:
// 8 edge streams x 8 lanes/edge; lane owns u16x8 chunks (c, c+8); fp32 accum.
__global__ void agg_bf_kernel(const int* __restrict__ nbr, const int* __restrict__ row_ptr,
                              const unsigned short* __restrict__ embb,
                              unsigned short* __restrict__ aggb, int N) {
    int n = blockIdx.x * 4 + (threadIdx.x >> 6);
    if (n >= N) return;
    int tt = threadIdx.x & 63;
    int c = tt & 7;       // chunk
    int j = tt >> 3;      // edge stream 0..7

    int lo = row_ptr[n], hi = row_ptr[n + 1];

    float s0[8], s1[8];
#pragma unroll
    for (int k = 0; k < 8; ++k) { s0[k] = 0.f; s1[k] = 0.f; }

    for (int e = lo + j; e < hi; e += 8) {
        const u16x8* r = (const u16x8*)(embb + (size_t)nbr[e] * D);
        u16x8 v0 = r[c];
        u16x8 v1 = r[c + 8];
#pragma unroll
        for (int k = 0; k < 8; ++k) { s0[k] += bf2f(v0[k]); s1[k] += bf2f(v1[k]); }
    }
#pragma unroll
    for (int k = 0; k < 8; ++k) { red3(s0[k]); red3(s1[k]); }

    if (j == 0) {
        u16x8 o0, o1;
#pragma unroll
        for (int k = 0; k < 8; ++k) { o0[k] = f2bf(s0[k]); o1[k] = f2bf(s1[k]); }
        u16x8* o = (u16x8*)(aggb + (size_t)n * D);
        o[c] = o0;
        o[c + 8] = o1;
    }
}

// Fallback: gather fp32 emb (when ws can't hold embb). 8 streams x 8 lanes,
// lane owns float4 chunks (c, c+8, c+16, c+24).
__global__ void agg_f32_kernel(const int* __restrict__ nbr, const int* __restrict__ row_ptr,
                               const float* __restrict__ emb,
                               unsigned short* __restrict__ aggb, int N) {
    int n = blockIdx.x * 4 + (threadIdx.x >> 6);
    if (n >= N) return;
    int tt = threadIdx.x & 63;
    int c = tt & 7;
    int j = tt >> 3;

    int lo = row_ptr[n], hi = row_ptr[n + 1];

    float4 s0 = make_float4(0.f, 0.f, 0.f, 0.f);
    float4 s1 = make_float4(0.f, 0.f, 0.f, 0.f);
    float4 s2 = make_float4(0.f, 0.f, 0.f, 0.f);
    float4 s3 = make_float4(0.f, 0.f, 0.f, 0.f);
    for (int e = lo + j; e < hi; e += 8) {
        const float4* r = (const float4*)&emb[(size_t)nbr[e] * D];
        float4 v0 = r[c], v1 = r[c + 8], v2 = r[c + 16], v3 = r[c + 24];
        s0.x += v0.x; s0.y += v0.y; s0.z += v0.z; s0.w += v0.w;
        s1.x += v1.x; s1.y += v1.y; s1.z += v1.z; s1.w += v1.w;
        s2.x += v2.x; s2.y += v2.y; s2.z += v2.z; s2.w += v2.w;
        s3.x += v3.x; s3.y += v3.y; s3.z += v3.z; s3.w += v3.w;
    }
    red3(s0.x); red3(s0.y); red3(s0.z); red3(s0.w);
    red3(s1.x); red3(s1.y); red3(s1.z); red3(s1.w);
    red3(s2.x); red3(s2.y); red3(s2.z); red3(s2.w);
    red3(s3.x); red3(s3.y); red3(s3.z); red3(s3.w);
    if (j == 0) {
        ushort4* o = (ushort4*)(aggb + (size_t)n * D);
        o[c]      = pack4(s0);
        o[c + 8]  = pack4(s1);
        o[c + 16] = pack4(s2);
        o[c + 24] = pack4(s3);
    }
}

// -------------------------------------------------------------------------
// MFMA matvec + relu + column-sum. Wave job = (dim-tile dt, node stripe);
// each wave handles ngroups/nstripes (=2) 16-node groups. X-fragments are
// gathered directly via node_ids (BF: bf16 table, else fp32 + in-reg pack).
// A-frag: A[m=lane&15][k=quad*8+j]; B-frag: B[k=quad*8+j][n=lane&15] = W[n][k]
// C/D: col=lane&15 (dim), row=quad*4+reg (node).
template <bool BF>
__global__ __launch_bounds__(256) void matvec_kernel(
    const int* __restrict__ node_ids, const void* __restrict__ embv,
    const unsigned short* __restrict__ aggb,
    const unsigned short* __restrict__ Wb, const unsigned short* __restrict__ Mb,
    float* __restrict__ rs, int N, int ngroups, int nstripes) {
    int t = threadIdx.x;
    int wid = blockIdx.x * 4 + (t >> 6);
    int l = t & 63;
    int quad = l >> 4, col = l & 15;
    int dt = wid & 7;
    int stripe = wid >> 3;

    bf16x8 bw[4], bm[4];
    int wrow = (dt * 16 + col) * D;
#pragma unroll
    for (int ks = 0; ks < 4; ++ks) {
        int off = wrow + ks * 32 + quad * 8;
        bw[ks] = *(const bf16x8*)(Wb + off);
        bm[ks] = *(const bf16x8*)(Mb + off);
    }

    const bf16x8 zero8 = {0, 0, 0, 0, 0, 0, 0, 0};
    float vsum = 0.f;

    for (int grp = stripe; grp < ngroups; grp += nstripes) {
        int node = grp * 16 + col;
        bool valid = node < N;
        int nid = valid ? node_ids[node] : 0;
        const unsigned short* ar = aggb + (size_t)node * D + quad * 8;

        f32x4 acc = {0.f, 0.f, 0.f, 0.f};
#pragma unroll
        for (int ks = 0; ks < 4; ++ks) {
            bf16x8 ax;
            if (BF) {
                const unsigned short* xr =
                    (const unsigned short*)embv + (size_t)nid * D + quad * 8;
                ax = valid ? *(const bf16x8*)(xr + ks * 32) : zero8;
            } else {
                if (valid) {
                    const float4* xf = (const float4*)((const float*)embv +
                                       (size_t)nid * D + quad * 8 + ks * 32);
                    ushort4 p0 = pack4(xf[0]);
                    ushort4 p1 = pack4(xf[1]);
                    ax[0] = (short)p0.x; ax[1] = (short)p0.y;
                    ax[2] = (short)p0.z; ax[3] = (short)p0.w;
                    ax[4] = (short)p1.x; ax[5] = (short)p1.y;
                    ax[6] = (short)p1.z; ax[7] = (short)p1.w;
                } else ax = zero8;
            }
            bf16x8 aa = valid ? *(const bf16x8*)(ar + ks * 32) : zero8;
            acc = __builtin_amdgcn_mfma_f32_16x16x32_bf16(ax, bw[ks], acc, 0, 0, 0);
            acc = __builtin_amdgcn_mfma_f32_16x16x32_bf16(aa, bm[ks], acc, 0, 0, 0);
        }
        vsum += fmaxf(acc[0], 0.f) + fmaxf(acc[1], 0.f)
              + fmaxf(acc[2], 0.f) + fmaxf(acc[3], 0.f);
    }

    vsum += __shfl_xor(vsum, 16);
    vsum += __shfl_xor(vsum, 32);
    if (l < 16) atomicAdd(&rs[(dt * 16 + col) * RS_STRIDE], vsum);
}

// -------------------------------------------------------------------------
__global__ void softmax_kernel(const float* __restrict__ rs, float* __restrict__ out) {
    int t = threadIdx.x;                 // 0..63
    float v0 = rs[t * RS_STRIDE];
    float v1 = rs[(t + 64) * RS_STRIDE];
    float m = fmaxf(v0, v1);
    for (int o = 32; o > 0; o >>= 1) m = fmaxf(m, __shfl_xor(m, o));
    float e0 = expf(v0 - m);
    float e1 = expf(v1 - m);
    float s = e0 + e1;
    for (int o = 32; o > 0; o >>= 1) s += __shfl_xor(s, o);
    float inv = 1.0f / s;
    out[t] = e0 * inv;
    out[t + 64] = e1 * inv;
}

extern "C" void kernel_launch(void* const* d_in, const int* in_sizes, int n_in,
                              void* d_out, int out_size, void* d_ws, size_t ws_size,
                              hipStream_t stream) {
    const int*   node_ids = (const int*)d_in[0];
    const int*   nbr      = (const int*)d_in[1];
    const int*   seg      = (const int*)d_in[2];
    const float* W        = (const float*)d_in[3];
    const float* M        = (const float*)d_in[4];
    const float* emb      = (const float*)d_in[5];
    float* out = (float*)d_out;

    int N = in_sizes[0];
    int E = in_sizes[1];
    long long VD = in_sizes[5];          // V*D elements
    int ngroups  = (N + 15) / 16;
    int nstripes = (ngroups + 1) / 2;    // each wave: exactly 2 groups
    int mv_blocks = 2 * nstripes;        // 8*nstripes waves / 4 waves-per-block

    // ws layout: aggb[N*D] u16 | Wb | Mb | rs fp32 | row_ptr int | embb[V*D] u16
    unsigned short* aggb = (unsigned short*)d_ws;
    unsigned short* Wb   = aggb + (size_t)N * D;
    unsigned short* Mb   = Wb + D * D;
    float* rs            = (float*)(Mb + D * D);
    int* row_ptr         = (int*)(rs + (size_t)D * RS_STRIDE);
    unsigned short* embb = (unsigned short*)(row_ptr + (N + 1));

    size_t need_bf = (size_t)(row_ptr + (N + 1) - (int*)d_ws) * 4 + (size_t)VD * 2;
    bool use_bf = ws_size >= need_bf;
    int n4 = use_bf ? (int)(VD / 4) : 0;
    int cvt_n = (n4 > 8192 ? n4 : 8192);

    convert_kernel<<<(cvt_n + 255) / 256, 256, 0, stream>>>(emb, W, M, embb, Wb, Mb, rs, n4);
    rowptr_kernel<<<(E + 255) / 256, 256, 0, stream>>>(seg, row_ptr, E, N);
    if (use_bf) {
        agg_bf_kernel<<<(N + 3) / 4, 256, 0, stream>>>(nbr, row_ptr, embb, aggb, N);
        matvec_kernel<true><<<mv_blocks, 256, 0, stream>>>(node_ids, embb, aggb, Wb, Mb,
                                                           rs, N, ngroups, nstripes);
    } else {
        agg_f32_kernel<<<(N + 3) / 4, 256, 0, stream>>>(nbr, row_ptr, emb, aggb, N);
        matvec_kernel<false><<<mv_blocks, 256, 0, stream>>>(node_ids, emb, aggb, Wb, Mb,
                                                            rs, N, ngroups, nstripes);
    }
    softmax_kernel<<<1, 64, 0, stream>>>(rs, out);
}